// Round 4
// baseline (631.987 us; speedup 1.0000x reference)
//
#include <hip/hip_runtime.h>

// Problem: T=128, B=64, STATE=32, LATENT=16, AC=8, MS=8, SE=64, AE=16, H=64, OUT=18
// d_out layout: [0] = kl_loss, [1 .. 8192] = recon_loss[s*64+b]  (out_size = 8193, f32)
// d_ws layout:  [0, 6291456)  xi  (T,B,192) f32   = embed@Wi + bi
//               [6291456, 8388608) hid0 (T,B,64) f32
//               [8388608, +32) 8 work-steal counters (one per XCD-queue)

#define XI_OFF   0
#define HID_OFF  6291456
#define CTR_OFF  8388608

typedef float f32x16 __attribute__((ext_vector_type(16)));
typedef _Float16 h2 __attribute__((ext_vector_type(2)));

#if __has_builtin(__builtin_amdgcn_fdot2)
#define DOT2(a, b, c) __builtin_amdgcn_fdot2((a), (b), (c), false)
#else
#define DOT2(a, b, c) ((c) + (float)(a).x * (float)(b).x + (float)(a).y * (float)(b).y)
#endif

// ---------------- Fused precompute (blocks 0..255) + KL (blocks 256..319) ----------------
__global__ __launch_bounds__(256, 1) void precompute_kernel(
    const float* __restrict__ state, const float* __restrict__ ac, const float* __restrict__ ms,
    const float* __restrict__ Wst, const float* __restrict__ bst,
    const float* __restrict__ Wac, const float* __restrict__ bac,
    const float* __restrict__ Wem, const float* __restrict__ bem,
    const float* __restrict__ Whd, const float* __restrict__ bhd,
    const float* __restrict__ Wi,  const float* __restrict__ bi,
    const float* __restrict__ lm, const float* __restrict__ lv,
    const float* __restrict__ lmt, const float* __restrict__ lvt,
    float* __restrict__ xi, float* __restrict__ hid0, float* __restrict__ out) {
  __shared__ float sWst[32 * 64];
  __shared__ float sWem[80 * 64];
  __shared__ float sWhd[24 * 64];
  __shared__ float sWac[8 * 16];
  __shared__ float sb[208];
  __shared__ float sin_[4][48];
  __shared__ float sse[4][80];
  __shared__ float semb[4][64];
  __shared__ float ps[4];
  int tid = threadIdx.x, lane = tid & 63, w = tid >> 6;

  if (blockIdx.x >= 256) {
    // ---- KL part: grid-stride over 128*64*32 items ----
    float total = 0.f;
    for (int it = 0; it < 16; ++it) {
      int idx = ((int)blockIdx.x - 256) * 256 + tid + it * 16384;
      int g = idx & 31;
      int pair = idx >> 5;
      const float* M = (g < 16) ? lm : lmt;
      const float* V = (g < 16) ? lv : lvt;
      int cur = pair * 16 + (g & 15);
      float mu = M[cur], lE = V[cur];
      float m = 0.f, lS = 0.f;
      if (pair >= 64) { m = M[cur - 1024]; lS = V[cur - 1024]; }
      float d = m - mu;
      total += 0.5f * (lS - lE - 1.f + __expf(lE - lS) + d * d * __expf(-lS));
    }
    #pragma unroll
    for (int off = 32; off; off >>= 1) total += __shfl_xor(total, off);
    if (lane == 0) ps[w] = total;
    __syncthreads();
    if (tid == 0) atomicAdd(out, ps[0] + ps[1] + ps[2] + ps[3]);
    return;
  }

  // ---- precompute part: 32 (t,b) pairs per block ----
  f32x16 wi0[4], wi1[4], wi2[4];
  #pragma unroll
  for (int k = 0; k < 64; ++k) {
    wi0[k >> 4][k & 15] = Wi[k * 192 + lane];
    wi1[k >> 4][k & 15] = Wi[k * 192 + 64 + lane];
    wi2[k >> 4][k & 15] = Wi[k * 192 + 128 + lane];
  }
  for (int i = tid; i < 32 * 64; i += 256) sWst[i] = Wst[i];
  for (int i = tid; i < 80 * 64; i += 256) sWem[i] = Wem[i];
  for (int i = tid; i < 24 * 64; i += 256) sWhd[i] = Whd[i];
  for (int i = tid; i < 8 * 16; i += 256) sWac[i] = Wac[i];
  if (tid < 64) sb[tid] = bst[tid];
  if (tid < 16) sb[64 + tid] = bac[tid];
  if (tid < 64) sb[80 + tid] = bem[tid];
  if (tid < 64) sb[144 + tid] = bhd[tid];
  float bi0 = bi[lane], bi1 = bi[64 + lane], bi2 = bi[128 + lane];
  __syncthreads();
  for (int cnt = 0; cnt < 8; ++cnt) {
    int pair = blockIdx.x * 32 + w * 8 + cnt;   // t*64 + b, in [0, 8192)
    if (lane < 32)      sin_[w][lane] = state[pair * 32 + lane];
    else if (lane < 40) sin_[w][lane] = ac[pair * 8 + (lane - 32)];
    else if (lane < 48) sin_[w][lane] = ms[pair * 8 + (lane - 40)];
    __syncthreads();
    float se = sb[lane];
    #pragma unroll
    for (int k = 0; k < 32; ++k) se += sin_[w][k] * sWst[k * 64 + lane];
    se = fmaxf(se, 0.f);
    float ae = 0.f;
    if (lane < 16) {
      ae = sb[64 + lane];
      #pragma unroll
      for (int k = 0; k < 8; ++k) ae += sin_[w][32 + k] * sWac[k * 16 + lane];
      ae = fmaxf(ae, 0.f);
    }
    __syncthreads();
    sse[w][lane] = se;
    if (lane < 16) sse[w][64 + lane] = ae;
    __syncthreads();
    float em = sb[80 + lane];
    #pragma unroll
    for (int k = 0; k < 80; ++k) em += sse[w][k] * sWem[k * 64 + lane];
    float hd = sb[144 + lane];
    #pragma unroll
    for (int k = 0; k < 16; ++k) hd += sse[w][64 + k] * sWhd[k * 64 + lane];
    #pragma unroll
    for (int k = 0; k < 8; ++k) hd += sin_[w][40 + k] * sWhd[(16 + k) * 64 + lane];
    hid0[pair * 64 + lane] = hd;
    semb[w][lane] = em;
    __syncthreads();
    float x0 = bi0, x1 = bi1, x2 = bi2;
    #pragma unroll
    for (int k = 0; k < 64; ++k) {
      float e = semb[w][k];
      x0 += e * wi0[k >> 4][k & 15];
      x1 += e * wi1[k >> 4][k & 15];
      x2 += e * wi2[k >> 4][k & 15];
    }
    float* xo = xi + pair * 192;
    xo[lane] = x0; xo[64 + lane] = x1; xo[128 + lane] = x2;
    __syncthreads();
  }
}

// ---------------- Rollout: one wave per (t,b) sequence ----------------
// f16-packed recurrent weights (96 VGPR) + v_dot2_f32_f16; one packed-h LDS
// broadcast per step feeds gates AND W_out row; 8 XCD-local work queues.
__global__ __launch_bounds__(64, 4) void rollout_kernel(
    const float* __restrict__ xi, const float* __restrict__ hid0,
    const float* __restrict__ dones, const int* __restrict__ actions,
    const float* __restrict__ Whrz, const float* __restrict__ Whn,
    const float* __restrict__ bhn, const float* __restrict__ Wout,
    const float* __restrict__ bout, float* __restrict__ out,
    unsigned int* __restrict__ ctrs) {
  __shared__ __attribute__((aligned(16))) h2 sWo2[18 * 36];  // row j at [j*36], 32 pairs + pad
  __shared__ __attribute__((aligned(16))) h2 sh2[32];        // packed h broadcast
  __shared__ __attribute__((aligned(16))) float slog[20];    // 18 logits + 2 sentinels
  __shared__ float sbo[18];
  int lane = threadIdx.x;
  h2 Wr[32], Wz[32], Wn[32];     // f16-packed recurrent columns: 96 VGPRs
  #pragma unroll
  for (int k = 0; k < 32; ++k) {
    Wr[k] = h2{(_Float16)Whrz[(2 * k) * 128 + lane],      (_Float16)Whrz[(2 * k + 1) * 128 + lane]};
    Wz[k] = h2{(_Float16)Whrz[(2 * k) * 128 + 64 + lane], (_Float16)Whrz[(2 * k + 1) * 128 + 64 + lane]};
    Wn[k] = h2{(_Float16)Whn[(2 * k) * 64 + lane],        (_Float16)Whn[(2 * k + 1) * 64 + lane]};
  }
  for (int i = lane; i < 18 * 32; i += 64) {
    int j = i >> 5, p = i & 31;
    sWo2[j * 36 + p] = h2{(_Float16)Wout[(2 * p) * 18 + j], (_Float16)Wout[(2 * p + 1) * 18 + j]};
  }
  if (lane < 18) sbo[lane] = bout[lane];
  if (lane < 2)  slog[18 + lane] = -3.0e38f;     // sentinels (exp -> 0)
  float bhn_r = bhn[lane];
  __syncthreads();
  int row = (lane < 18) ? lane : 0;
  int q = blockIdx.x & 7;                        // ~XCD id under round-robin dispatch
  const uint4* shv = (const uint4*)sh2;
  const uint4* wrow = (const uint4*)&sWo2[row * 36];
  while (true) {
    int i = 0;
    if (lane == 0) i = (int)atomicAdd(&ctrs[q], 1u);
    i = __shfl(i, 0);
    if (i >= 1024) break;
    int t = i >> 3, b = ((i & 7) << 3) | q;      // queue q owns b with b&7==q; t-ascending (LPT)
    int u = t;
    float h = hid0[(t * 64 + b) * 64 + lane];
    const float* xb = xi + (t * 64 + b) * 192;
    float x0 = xb[lane], x1 = xb[64 + lane], x2 = xb[128 + lane];
    float d = dones[t * 64 + b];
    int  act = actions[t * 64 + b];
    for (int s = 0;; ++s) {
      int un = (u < 127) ? u + 1 : 127;
      // -------- prefetch next step --------
      const float* xn = xi + (un * 64 + b) * 192;
      float nx0 = xn[lane], nx1 = xn[64 + lane], nx2 = xn[128 + lane];
      float nd = dones[un * 64 + b];
      int   na = actions[un * 64 + b];
      float nh = hid0[(un * 64 + b) * 64 + lane];
      // -------- broadcast h as packed f16 pairs --------
      float hp = __shfl_xor(h, 1);
      if ((lane & 1) == 0) sh2[lane >> 1] = h2{(_Float16)h, (_Float16)hp};
      // -------- GRU gates via v_dot2_f32_f16 --------
      float ar = x0, az = x1, an = 0.f;
      #pragma unroll
      for (int qq = 0; qq < 8; ++qq) {
        uint4 hv = shv[qq];                       // same addr all lanes: broadcast
        h2 a0 = __builtin_bit_cast(h2, hv.x);
        h2 a1 = __builtin_bit_cast(h2, hv.y);
        h2 a2 = __builtin_bit_cast(h2, hv.z);
        h2 a3 = __builtin_bit_cast(h2, hv.w);
        ar = DOT2(a0, Wr[4 * qq + 0], ar); ar = DOT2(a1, Wr[4 * qq + 1], ar);
        ar = DOT2(a2, Wr[4 * qq + 2], ar); ar = DOT2(a3, Wr[4 * qq + 3], ar);
        az = DOT2(a0, Wz[4 * qq + 0], az); az = DOT2(a1, Wz[4 * qq + 1], az);
        az = DOT2(a2, Wz[4 * qq + 2], az); az = DOT2(a3, Wz[4 * qq + 3], az);
        an = DOT2(a0, Wn[4 * qq + 0], an); an = DOT2(a1, Wn[4 * qq + 1], an);
        an = DOT2(a2, Wn[4 * qq + 2], an); an = DOT2(a3, Wn[4 * qq + 3], an);
      }
      float r = 1.f / (1.f + __expf(-ar));
      float z = 1.f / (1.f + __expf(-az));
      float pre = x2 + r * (an + bhn_r);
      float n = 1.f - 2.f / (1.f + __expf(2.f * pre));       // tanh
      h = (1.f - z) * n + z * h;
      // -------- broadcast h_new packed; logits on lanes 0..17 --------
      float hq = __shfl_xor(h, 1);
      if ((lane & 1) == 0) sh2[lane >> 1] = h2{(_Float16)h, (_Float16)hq};
      float acc = sbo[row];
      #pragma unroll
      for (int qq = 0; qq < 8; ++qq) {
        uint4 hv = shv[qq];
        uint4 wv = wrow[qq];
        acc = DOT2(__builtin_bit_cast(h2, hv.x), __builtin_bit_cast(h2, wv.x), acc);
        acc = DOT2(__builtin_bit_cast(h2, hv.y), __builtin_bit_cast(h2, wv.y), acc);
        acc = DOT2(__builtin_bit_cast(h2, hv.z), __builtin_bit_cast(h2, wv.z), acc);
        acc = DOT2(__builtin_bit_cast(h2, hv.w), __builtin_bit_cast(h2, wv.w), acc);
      }
      if (lane < 18) slog[lane] = acc;
      // -------- softmax: LDS gather, in-register reduce --------
      float4 L0 = *(const float4*)&slog[0];
      float4 L1 = *(const float4*)&slog[4];
      float4 L2 = *(const float4*)&slog[8];
      float4 L3 = *(const float4*)&slog[12];
      float4 L4 = *(const float4*)&slog[16];
      float m0 = fmaxf(fmaxf(L0.x, L0.y), fmaxf(L0.z, L0.w));
      float m1 = fmaxf(fmaxf(L1.x, L1.y), fmaxf(L1.z, L1.w));
      float m2 = fmaxf(fmaxf(L2.x, L2.y), fmaxf(L2.z, L2.w));
      float m3 = fmaxf(fmaxf(L3.x, L3.y), fmaxf(L3.z, L3.w));
      float m4 = fmaxf(fmaxf(L4.x, L4.y), fmaxf(L4.z, L4.w));
      float mx = fmaxf(fmaxf(fmaxf(m0, m1), fmaxf(m2, m3)), m4);
      float s0 = __expf(L0.x - mx) + __expf(L0.y - mx) + __expf(L0.z - mx) + __expf(L0.w - mx);
      float s1 = __expf(L1.x - mx) + __expf(L1.y - mx) + __expf(L1.z - mx) + __expf(L1.w - mx);
      float s2 = __expf(L2.x - mx) + __expf(L2.y - mx) + __expf(L2.z - mx) + __expf(L2.w - mx);
      float s3 = __expf(L3.x - mx) + __expf(L3.y - mx) + __expf(L3.z - mx) + __expf(L3.w - mx);
      float s4 = __expf(L4.x - mx) + __expf(L4.y - mx) + __expf(L4.z - mx) + __expf(L4.w - mx);
      float ssum = (s0 + s1) + (s2 + s3) + s4;
      float la = slog[act];
      float lse = mx + __logf(ssum);
      if (lane == 0) atomicAdd(&out[1 + s * 64 + b], lse - la);
      if (d > 0.f || u == 127) break;
      // -------- advance --------
      u = un; x0 = nx0; x1 = nx1; x2 = nx2; d = nd; act = na;
      if (nd > 0.f) h = nh;
    }
  }
}

extern "C" void kernel_launch(void* const* d_in, const int* in_sizes, int n_in,
                              void* d_out, int out_size, void* d_ws, size_t ws_size,
                              hipStream_t stream) {
  const float* state = (const float*)d_in[0];
  const float* lm    = (const float*)d_in[1];
  const float* lv    = (const float*)d_in[2];
  const float* lmt   = (const float*)d_in[3];
  const float* lvt   = (const float*)d_in[4];
  const float* ac    = (const float*)d_in[5];
  const float* ms    = (const float*)d_in[6];
  const int*   actions = (const int*)d_in[7];
  const float* dones = (const float*)d_in[8];
  const float* Wst = (const float*)d_in[9],  *bst = (const float*)d_in[10];
  const float* Wac = (const float*)d_in[11], *bac = (const float*)d_in[12];
  const float* Wem = (const float*)d_in[13], *bem = (const float*)d_in[14];
  const float* Whd = (const float*)d_in[15], *bhd = (const float*)d_in[16];
  const float* Wi  = (const float*)d_in[17], *bi  = (const float*)d_in[18];
  const float* Whrz = (const float*)d_in[19];
  const float* Whn  = (const float*)d_in[20], *bhn = (const float*)d_in[21];
  const float* Wout = (const float*)d_in[22], *bout = (const float*)d_in[23];
  float* out = (float*)d_out;
  float* xi   = (float*)((char*)d_ws + XI_OFF);
  float* hid0 = (float*)((char*)d_ws + HID_OFF);
  unsigned int* ctrs = (unsigned int*)((char*)d_ws + CTR_OFF);

  hipMemsetAsync(d_out, 0, (size_t)out_size * sizeof(float), stream);
  hipMemsetAsync(ctrs, 0, 8 * sizeof(unsigned int), stream);

  hipLaunchKernelGGL(precompute_kernel, dim3(320), dim3(256), 0, stream,
                     state, ac, ms, Wst, bst, Wac, bac, Wem, bem, Whd, bhd, Wi, bi,
                     lm, lv, lmt, lvt, xi, hid0, out);
  hipLaunchKernelGGL(rollout_kernel, dim3(4096), dim3(64), 0, stream,
                     xi, hid0, dones, actions, Whrz, Whn, bhn, Wout, bout, out, ctrs);
}

// Round 5
// 415.587 us; speedup vs baseline: 1.5207x; 1.5207x over previous
//
#include <hip/hip_runtime.h>

// Problem: T=128, B=64, STATE=32, LATENT=16, AC=8, MS=8, SE=64, AE=16, H=64, OUT=18
// d_out layout: [0] = kl_loss, [1 .. 8192] = recon_loss[s*64+b]  (out_size = 8193, f32)
// d_ws layout:  [0, 6291456)  xi  (T,B,192) f32   = embed@Wi + bi
//               [6291456, 8388608) hid0 (T,B,64) f32
//               [8388608, +4) work-steal counter

#define XI_OFF   0
#define HID_OFF  6291456
#define CTR_OFF  8388608

typedef float f32x2  __attribute__((ext_vector_type(2)));
typedef float f32x16 __attribute__((ext_vector_type(16)));

// ---------------- Fused precompute (blocks 0..63) + KL (blocks 64..127) ----------------
__global__ __launch_bounds__(256, 1) void precompute_kernel(
    const float* __restrict__ state, const float* __restrict__ ac, const float* __restrict__ ms,
    const float* __restrict__ Wst, const float* __restrict__ bst,
    const float* __restrict__ Wac, const float* __restrict__ bac,
    const float* __restrict__ Wem, const float* __restrict__ bem,
    const float* __restrict__ Whd, const float* __restrict__ bhd,
    const float* __restrict__ Wi,  const float* __restrict__ bi,
    const float* __restrict__ lm, const float* __restrict__ lv,
    const float* __restrict__ lmt, const float* __restrict__ lvt,
    float* __restrict__ xi, float* __restrict__ hid0, float* __restrict__ out) {
  __shared__ float sWst[32 * 64];
  __shared__ float sWem[80 * 64];
  __shared__ float sWhd[24 * 64];
  __shared__ float sWac[8 * 16];
  __shared__ float sb[208];
  __shared__ float sin_[4][48];
  __shared__ float sse[4][80];
  __shared__ float semb[4][64];
  __shared__ float ps[4];
  int tid = threadIdx.x, lane = tid & 63, w = tid >> 6;

  if (blockIdx.x >= 64) {
    // ---- KL: 64 blocks * 256 threads * 16 iters = 262144 items ----
    float total = 0.f;
    for (int it = 0; it < 16; ++it) {
      int idx = ((int)blockIdx.x - 64) * 256 + tid + it * 16384;
      int g = idx & 31;
      int pair = idx >> 5;
      const float* M = (g < 16) ? lm : lmt;
      const float* V = (g < 16) ? lv : lvt;
      int cur = pair * 16 + (g & 15);
      float mu = M[cur], lE = V[cur];
      float m = 0.f, lS = 0.f;
      if (pair >= 64) { m = M[cur - 1024]; lS = V[cur - 1024]; }
      float d = m - mu;
      total += 0.5f * (lS - lE - 1.f + __expf(lE - lS) + d * d * __expf(-lS));
    }
    #pragma unroll
    for (int off = 32; off; off >>= 1) total += __shfl_xor(total, off);
    if (lane == 0) ps[w] = total;
    __syncthreads();
    if (tid == 0) atomicAdd(out, ps[0] + ps[1] + ps[2] + ps[3]);
    return;
  }

  // ---- precompute: 128 (t,b) pairs per block ----
  f32x16 wi0[4], wi1[4], wi2[4];
  #pragma unroll
  for (int k = 0; k < 64; ++k) {
    wi0[k >> 4][k & 15] = Wi[k * 192 + lane];
    wi1[k >> 4][k & 15] = Wi[k * 192 + 64 + lane];
    wi2[k >> 4][k & 15] = Wi[k * 192 + 128 + lane];
  }
  for (int i = tid; i < 32 * 64; i += 256) sWst[i] = Wst[i];
  for (int i = tid; i < 80 * 64; i += 256) sWem[i] = Wem[i];
  for (int i = tid; i < 24 * 64; i += 256) sWhd[i] = Whd[i];
  for (int i = tid; i < 8 * 16; i += 256) sWac[i] = Wac[i];
  if (tid < 64) sb[tid] = bst[tid];
  if (tid < 16) sb[64 + tid] = bac[tid];
  if (tid < 64) sb[80 + tid] = bem[tid];
  if (tid < 64) sb[144 + tid] = bhd[tid];
  float bi0 = bi[lane], bi1 = bi[64 + lane], bi2 = bi[128 + lane];
  __syncthreads();
  for (int cnt = 0; cnt < 32; ++cnt) {
    int pair = blockIdx.x * 128 + w * 32 + cnt;   // t*64 + b, in [0, 8192)
    if (lane < 32)      sin_[w][lane] = state[pair * 32 + lane];
    else if (lane < 40) sin_[w][lane] = ac[pair * 8 + (lane - 32)];
    else if (lane < 48) sin_[w][lane] = ms[pair * 8 + (lane - 40)];
    __syncthreads();
    float se = sb[lane];
    #pragma unroll
    for (int k = 0; k < 32; ++k) se += sin_[w][k] * sWst[k * 64 + lane];
    se = fmaxf(se, 0.f);
    float ae = 0.f;
    if (lane < 16) {
      ae = sb[64 + lane];
      #pragma unroll
      for (int k = 0; k < 8; ++k) ae += sin_[w][32 + k] * sWac[k * 16 + lane];
      ae = fmaxf(ae, 0.f);
    }
    __syncthreads();
    sse[w][lane] = se;
    if (lane < 16) sse[w][64 + lane] = ae;
    __syncthreads();
    float em = sb[80 + lane];
    #pragma unroll
    for (int k = 0; k < 80; ++k) em += sse[w][k] * sWem[k * 64 + lane];
    float hd = sb[144 + lane];
    #pragma unroll
    for (int k = 0; k < 16; ++k) hd += sse[w][64 + k] * sWhd[k * 64 + lane];
    #pragma unroll
    for (int k = 0; k < 8; ++k) hd += sin_[w][40 + k] * sWhd[(16 + k) * 64 + lane];
    hid0[pair * 64 + lane] = hd;
    semb[w][lane] = em;
    __syncthreads();
    float x0 = bi0, x1 = bi1, x2 = bi2;
    #pragma unroll
    for (int k = 0; k < 64; ++k) {
      float e = semb[w][k];
      x0 += e * wi0[k >> 4][k & 15];
      x1 += e * wi1[k >> 4][k & 15];
      x2 += e * wi2[k >> 4][k & 15];
    }
    float* xo = xi + pair * 192;
    xo[lane] = x0; xo[64 + lane] = x1; xo[128 + lane] = x2;
    __syncthreads();
  }
}

// ---------------- Rollout: 2 sequences per wave (ILP2), deferred logits ----------------

#define POPX(LIVE, U, S, B, H, X0, X1, X2, D, ACT, SH) { \
  int _i = 0; \
  if (lane == 0) _i = (int)atomicAdd(ctr, 1u); \
  _i = __shfl(_i, 0); \
  if (_i < 8192) { \
    B = _i & 63; U = _i >> 6; S = 0; \
    int _pr = (U << 6) | B; \
    H = hid0[_pr * 64 + lane]; \
    const float* _xp = xi + _pr * 192; \
    X0 = _xp[lane]; X1 = _xp[64 + lane]; X2 = _xp[128 + lane]; \
    D = dones[_pr]; ACT = actions[_pr]; \
    SH[lane] = H; LIVE = true; \
  } else { LIVE = false; } }

#define FLUSH_PEND(SH, SLOG, SLOGE, PV, PACT, PS, B) \
  if (PV) { \
    float _acc = bo_r; \
    _Pragma("unroll") \
    for (int _q = 0; _q < 16; ++_q) { \
      float4 _h4 = *(const float4*)&SH[_q * 4]; \
      float4 _w4 = *(const float4*)&sWoT[row * 68 + _q * 4]; \
      _acc += _h4.x * _w4.x + _h4.y * _w4.y + _h4.z * _w4.z + _h4.w * _w4.w; \
    } \
    SLOG[lane] = _acc; \
    SLOGE[lane] = __expf(_acc); \
    float4 _e0 = *(const float4*)&SLOGE[0], _e1 = *(const float4*)&SLOGE[4]; \
    float4 _e2 = *(const float4*)&SLOGE[8], _e3 = *(const float4*)&SLOGE[12]; \
    float2 _e4 = *(const float2*)&SLOGE[16]; \
    float _ss = (((_e0.x+_e0.y)+(_e0.z+_e0.w)) + ((_e1.x+_e1.y)+(_e1.z+_e1.w))) \
              + (((_e2.x+_e2.y)+(_e2.z+_e2.w)) + ((_e3.x+_e3.y)+(_e3.z+_e3.w))) + (_e4.x+_e4.y); \
    float _la = SLOG[PACT]; \
    if (lane == 0) atomicAdd(&out[1 + PS * 64 + B], __logf(_ss) - _la); \
  }

// branch-free main step for one slot; emits deferred logits of previous step
#define SLOT_MAIN(SH, SLOG, SLOGE, LIVE, U, S, B, H, X0, X1, X2, D, ACT, PV, PACT, PS, FR, DIRTY, EMIT, VAL, EPS) { \
  int _un = (U < 127) ? U + 1 : 127; \
  int _prn = (_un << 6) | B; \
  const float* _xn = xi + _prn * 192; \
  float _nx0 = _xn[lane], _nx1 = _xn[64 + lane], _nx2 = _xn[128 + lane]; \
  float _nd = dones[_prn]; \
  int   _na = actions[_prn]; \
  float _nh = hid0[_prn * 64 + lane]; \
  f32x2 _ar2 = {0.f,0.f}, _az2 = {0.f,0.f}, _an2 = {0.f,0.f}, _ac2 = {0.f,0.f}; \
  _Pragma("unroll") \
  for (int _q = 0; _q < 16; ++_q) { \
    float4 _h4 = *(const float4*)&SH[_q * 4]; \
    float4 _w4 = *(const float4*)&sWoT[row * 68 + _q * 4]; \
    f32x2 _pA = {_h4.x, _h4.y}, _pB = {_h4.z, _h4.w}; \
    _ar2 += _pA * Wr[2*_q]; _ar2 += _pB * Wr[2*_q+1]; \
    _az2 += _pA * Wz[2*_q]; _az2 += _pB * Wz[2*_q+1]; \
    _an2 += _pA * Wn[2*_q]; _an2 += _pB * Wn[2*_q+1]; \
    _ac2 += _pA * f32x2{_w4.x, _w4.y}; _ac2 += _pB * f32x2{_w4.z, _w4.w}; \
  } \
  float _acc = bo_r + _ac2.x + _ac2.y; \
  SLOG[lane] = _acc; \
  SLOGE[lane] = __expf(_acc); \
  float _ar = X0 + _ar2.x + _ar2.y; \
  float _az = X1 + _az2.x + _az2.y; \
  float _r = __builtin_amdgcn_rcpf(1.f + __expf(-_ar)); \
  float _z = __builtin_amdgcn_rcpf(1.f + __expf(-_az)); \
  float _pre = X2 + _r * (_an2.x + _an2.y + bhn_r); \
  float _n = 1.f - 2.f * __builtin_amdgcn_rcpf(1.f + __expf(2.f * _pre)); \
  float _hn = (1.f - _z) * _n + _z * H; \
  float4 _e0 = *(const float4*)&SLOGE[0], _e1 = *(const float4*)&SLOGE[4]; \
  float4 _e2 = *(const float4*)&SLOGE[8], _e3 = *(const float4*)&SLOGE[12]; \
  float2 _e4 = *(const float2*)&SLOGE[16]; \
  float _ss = (((_e0.x+_e0.y)+(_e0.z+_e0.w)) + ((_e1.x+_e1.y)+(_e1.z+_e1.w))) \
            + (((_e2.x+_e2.y)+(_e2.z+_e2.w)) + ((_e3.x+_e3.y)+(_e3.z+_e3.w))) + (_e4.x+_e4.y); \
  float _la = SLOG[PACT]; \
  EMIT = PV; VAL = __logf(_ss) - _la; EPS = PS; \
  SH[lane] = _hn; \
  PV = LIVE; PACT = ACT; PS = S; \
  bool _end = (D > 0.f) || (U == 127); \
  bool _rst = (!_end) && (_nd > 0.f); \
  FR = _end; DIRTY = _rst; \
  H = _rst ? _nh : _hn; \
  U  = _end ? U  : _un; \
  X0 = _end ? X0 : _nx0; X1 = _end ? X1 : _nx1; X2 = _end ? X2 : _nx2; \
  D  = _end ? D  : _nd; \
  ACT = _end ? ACT : _na; \
  S  = _end ? S : S + 1; }

__global__ __launch_bounds__(64, 1) void rollout_kernel(
    const float* __restrict__ xi, const float* __restrict__ hid0,
    const float* __restrict__ dones, const int* __restrict__ actions,
    const float* __restrict__ Whrz, const float* __restrict__ Whn,
    const float* __restrict__ bhn, const float* __restrict__ Wout,
    const float* __restrict__ bout, float* __restrict__ out,
    unsigned int* __restrict__ ctr) {
  __shared__ __attribute__((aligned(16))) float sWoT[18 * 68];  // [j][k], stride 68
  __shared__ __attribute__((aligned(16))) float shA[64], shB[64];
  __shared__ __attribute__((aligned(16))) float slogA[64], slogEA[64];
  __shared__ __attribute__((aligned(16))) float slogB[64], slogEB[64];
  int lane = threadIdx.x;
  f32x2 Wr[32], Wz[32], Wn[32];   // f32 recurrent weight columns (proven no-scratch codegen)
  #pragma unroll
  for (int k = 0; k < 32; ++k) {
    Wr[k] = f32x2{Whrz[(2*k) * 128 + lane],      Whrz[(2*k+1) * 128 + lane]};
    Wz[k] = f32x2{Whrz[(2*k) * 128 + 64 + lane], Whrz[(2*k+1) * 128 + 64 + lane]};
    Wn[k] = f32x2{Whn[(2*k) * 64 + lane],        Whn[(2*k+1) * 64 + lane]};
  }
  for (int i = lane; i < 18 * 64; i += 64) {
    int j = i >> 6, k = i & 63;
    sWoT[j * 68 + k] = Wout[k * 18 + j];          // transposed: [j][k]
  }
  int row = (lane < 18) ? lane : 0;
  float bo_r = bout[row];
  float bhn_r = bhn[lane];
  __syncthreads();

  // slot state
  bool liveA, liveB, pvA = false, pvB = false, frA = false, frB = false, dyA = false, dyB = false;
  int uA = 0, uB = 0, sA = 0, sB = 0, bA = 0, bB = 0, actA = 0, actB = 0, pactA = 0, pactB = 0, psA = 0, psB = 0;
  float hA = 0.f, hB = 0.f, xA0 = 0.f, xA1 = 0.f, xA2 = 0.f, xB0 = 0.f, xB1 = 0.f, xB2 = 0.f, dA = 1.f, dB = 1.f;

  POPX(liveA, uA, sA, bA, hA, xA0, xA1, xA2, dA, actA, shA);
  POPX(liveB, uB, sB, bB, hB, xB0, xB1, xB2, dB, actB, shB);

  while (liveA || liveB) {
    // ---- fixups (uniform, rare) ----
    if (frA || dyA) {
      FLUSH_PEND(shA, slogA, slogEA, pvA, pactA, psA, bA);
      pvA = false;
      if (frA) { frA = false; if (liveA) POPX(liveA, uA, sA, bA, hA, xA0, xA1, xA2, dA, actA, shA); }
      else     { shA[lane] = hA; dyA = false; }
    }
    if (frB || dyB) {
      FLUSH_PEND(shB, slogB, slogEB, pvB, pactB, psB, bB);
      pvB = false;
      if (frB) { frB = false; if (liveB) POPX(liveB, uB, sB, bB, hB, xB0, xB1, xB2, dB, actB, shB); }
      else     { shB[lane] = hB; dyB = false; }
    }
    // ---- branch-free mains (one basic block -> static A/B interleave) ----
    bool emA, emB; float vA, vB; int epA, epB;
    SLOT_MAIN(shA, slogA, slogEA, liveA, uA, sA, bA, hA, xA0, xA1, xA2, dA, actA, pvA, pactA, psA, frA, dyA, emA, vA, epA);
    SLOT_MAIN(shB, slogB, slogEB, liveB, uB, sB, bB, hB, xB0, xB1, xB2, dB, actB, pvB, pactB, psB, frB, dyB, emB, vB, epB);
    // ---- emissions at end (keeps mains branch-free) ----
    if (lane == 0) {
      if (emA) atomicAdd(&out[1 + epA * 64 + bA], vA);
      if (emB) atomicAdd(&out[1 + epB * 64 + bB], vB);
    }
  }
}

extern "C" void kernel_launch(void* const* d_in, const int* in_sizes, int n_in,
                              void* d_out, int out_size, void* d_ws, size_t ws_size,
                              hipStream_t stream) {
  const float* state = (const float*)d_in[0];
  const float* lm    = (const float*)d_in[1];
  const float* lv    = (const float*)d_in[2];
  const float* lmt   = (const float*)d_in[3];
  const float* lvt   = (const float*)d_in[4];
  const float* ac    = (const float*)d_in[5];
  const float* ms    = (const float*)d_in[6];
  const int*   actions = (const int*)d_in[7];
  const float* dones = (const float*)d_in[8];
  const float* Wst = (const float*)d_in[9],  *bst = (const float*)d_in[10];
  const float* Wac = (const float*)d_in[11], *bac = (const float*)d_in[12];
  const float* Wem = (const float*)d_in[13], *bem = (const float*)d_in[14];
  const float* Whd = (const float*)d_in[15], *bhd = (const float*)d_in[16];
  const float* Wi  = (const float*)d_in[17], *bi  = (const float*)d_in[18];
  const float* Whrz = (const float*)d_in[19];
  const float* Whn  = (const float*)d_in[20], *bhn = (const float*)d_in[21];
  const float* Wout = (const float*)d_in[22], *bout = (const float*)d_in[23];
  float* out = (float*)d_out;
  float* xi   = (float*)((char*)d_ws + XI_OFF);
  float* hid0 = (float*)((char*)d_ws + HID_OFF);
  unsigned int* ctr = (unsigned int*)((char*)d_ws + CTR_OFF);

  hipMemsetAsync(d_out, 0, (size_t)out_size * sizeof(float), stream);
  hipMemsetAsync(ctr, 0, sizeof(unsigned int), stream);

  hipLaunchKernelGGL(precompute_kernel, dim3(128), dim3(256), 0, stream,
                     state, ac, ms, Wst, bst, Wac, bac, Wem, bem, Whd, bhd, Wi, bi,
                     lm, lv, lmt, lvt, xi, hid0, out);
  hipLaunchKernelGGL(rollout_kernel, dim3(2048), dim3(64), 0, stream,
                     xi, hid0, dones, actions, Whrz, Whn, bhn, Wout, bout, out, ctr);
}

// Round 7
// 377.263 us; speedup vs baseline: 1.6752x; 1.1016x over previous
//
#include <hip/hip_runtime.h>

// Problem: T=128, B=64, STATE=32, LATENT=16, AC=8, MS=8, SE=64, AE=16, H=64, OUT=18
// d_out layout: [0] = kl_loss, [1 .. 8192] = recon_loss[s*64+b]  (out_size = 8193, f32)
// d_ws layout:  [0, 6291456)  xi  (T,B,192) f32   = embed@Wi + bi
//               [6291456, 8388608) hid0 (T,B,64) f32
//               [8388608, +4) work-steal counter

#define XI_OFF   0
#define HID_OFF  6291456
#define CTR_OFF  8388608

typedef float f32x16 __attribute__((ext_vector_type(16)));
typedef _Float16 h2 __attribute__((ext_vector_type(2)));

#if __has_builtin(__builtin_amdgcn_fdot2)
#define DOT2(a, b, c) __builtin_amdgcn_fdot2((a), (b), (c), false)
#else
#define DOT2(a, b, c) ((c) + (float)(a).x * (float)(b).x + (float)(a).y * (float)(b).y)
#endif

// pack {h[lane], h[lane^1]} into h2 using DPP quad_perm [1,0,3,2] (VALU, no LDS)
__device__ __forceinline__ h2 pack_pair(float h) {
  int hb = __builtin_bit_cast(int, h);
  int hp = __builtin_amdgcn_mov_dpp(hb, 0xB1, 0xF, 0xF, true);  // lane^1
  return __builtin_bit_cast(h2, __builtin_amdgcn_cvt_pkrtz(h, __builtin_bit_cast(float, hp)));
}

// ---------------- Fused precompute (blocks 0..255) + KL (blocks 256..319) ----------------
__global__ __launch_bounds__(256, 1) void precompute_kernel(
    const float* __restrict__ state, const float* __restrict__ ac, const float* __restrict__ ms,
    const float* __restrict__ Wst, const float* __restrict__ bst,
    const float* __restrict__ Wac, const float* __restrict__ bac,
    const float* __restrict__ Wem, const float* __restrict__ bem,
    const float* __restrict__ Whd, const float* __restrict__ bhd,
    const float* __restrict__ Wi,  const float* __restrict__ bi,
    const float* __restrict__ lm, const float* __restrict__ lv,
    const float* __restrict__ lmt, const float* __restrict__ lvt,
    float* __restrict__ xi, float* __restrict__ hid0, float* __restrict__ out) {
  __shared__ float sWst[32 * 64];
  __shared__ float sWem[80 * 64];
  __shared__ float sWhd[24 * 64];
  __shared__ float sWac[8 * 16];
  __shared__ float sb[208];
  __shared__ float sin_[4][48];
  __shared__ float sse[4][80];
  __shared__ float semb[4][64];
  __shared__ float ps[4];
  int tid = threadIdx.x, lane = tid & 63, w = tid >> 6;

  if (blockIdx.x >= 256) {
    // ---- KL: 64 blocks * 256 threads * 16 iters = 262144 items ----
    float total = 0.f;
    for (int it = 0; it < 16; ++it) {
      int idx = ((int)blockIdx.x - 256) * 256 + tid + it * 16384;
      int g = idx & 31;
      int pair = idx >> 5;
      const float* M = (g < 16) ? lm : lmt;
      const float* V = (g < 16) ? lv : lvt;
      int cur = pair * 16 + (g & 15);
      float mu = M[cur], lE = V[cur];
      float m = 0.f, lS = 0.f;
      if (pair >= 64) { m = M[cur - 1024]; lS = V[cur - 1024]; }
      float d = m - mu;
      total += 0.5f * (lS - lE - 1.f + __expf(lE - lS) + d * d * __expf(-lS));
    }
    #pragma unroll
    for (int off = 32; off; off >>= 1) total += __shfl_xor(total, off);
    if (lane == 0) ps[w] = total;
    __syncthreads();
    if (tid == 0) atomicAdd(out, ps[0] + ps[1] + ps[2] + ps[3]);
    return;
  }

  // ---- precompute: 32 (t,b) pairs per block ----
  f32x16 wi0[4], wi1[4], wi2[4];
  #pragma unroll
  for (int k = 0; k < 64; ++k) {
    wi0[k >> 4][k & 15] = Wi[k * 192 + lane];
    wi1[k >> 4][k & 15] = Wi[k * 192 + 64 + lane];
    wi2[k >> 4][k & 15] = Wi[k * 192 + 128 + lane];
  }
  for (int i = tid; i < 32 * 64; i += 256) sWst[i] = Wst[i];
  for (int i = tid; i < 80 * 64; i += 256) sWem[i] = Wem[i];
  for (int i = tid; i < 24 * 64; i += 256) sWhd[i] = Whd[i];
  for (int i = tid; i < 8 * 16; i += 256) sWac[i] = Wac[i];
  if (tid < 64) sb[tid] = bst[tid];
  if (tid < 16) sb[64 + tid] = bac[tid];
  if (tid < 64) sb[80 + tid] = bem[tid];
  if (tid < 64) sb[144 + tid] = bhd[tid];
  float bi0 = bi[lane], bi1 = bi[64 + lane], bi2 = bi[128 + lane];
  __syncthreads();
  for (int cnt = 0; cnt < 8; ++cnt) {
    int pair = blockIdx.x * 32 + w * 8 + cnt;   // t*64 + b, in [0, 8192)
    if (lane < 32)      sin_[w][lane] = state[pair * 32 + lane];
    else if (lane < 40) sin_[w][lane] = ac[pair * 8 + (lane - 32)];
    else if (lane < 48) sin_[w][lane] = ms[pair * 8 + (lane - 40)];
    __syncthreads();
    float se = sb[lane];
    #pragma unroll
    for (int k = 0; k < 32; ++k) se += sin_[w][k] * sWst[k * 64 + lane];
    se = fmaxf(se, 0.f);
    float ae = 0.f;
    if (lane < 16) {
      ae = sb[64 + lane];
      #pragma unroll
      for (int k = 0; k < 8; ++k) ae += sin_[w][32 + k] * sWac[k * 16 + lane];
      ae = fmaxf(ae, 0.f);
    }
    __syncthreads();
    sse[w][lane] = se;
    if (lane < 16) sse[w][64 + lane] = ae;
    __syncthreads();
    float em = sb[80 + lane];
    #pragma unroll
    for (int k = 0; k < 80; ++k) em += sse[w][k] * sWem[k * 64 + lane];
    float hd = sb[144 + lane];
    #pragma unroll
    for (int k = 0; k < 16; ++k) hd += sse[w][64 + k] * sWhd[k * 64 + lane];
    #pragma unroll
    for (int k = 0; k < 8; ++k) hd += sin_[w][40 + k] * sWhd[(16 + k) * 64 + lane];
    hid0[pair * 64 + lane] = hd;
    semb[w][lane] = em;
    __syncthreads();
    float x0 = bi0, x1 = bi1, x2 = bi2;
    #pragma unroll
    for (int k = 0; k < 64; ++k) {
      float e = semb[w][k];
      x0 += e * wi0[k >> 4][k & 15];
      x1 += e * wi1[k >> 4][k & 15];
      x2 += e * wi2[k >> 4][k & 15];
    }
    float* xo = xi + pair * 192;
    xo[lane] = x0; xo[64 + lane] = x1; xo[128 + lane] = x2;
    __syncthreads();
  }
}

// ---------------- Rollout: one wave per (t,b) sequence, work-stealing ----------------
// f16 weights + dot2 (96 VGPR); f16 h broadcast (DPP pack, 8 uniform b128 reads);
// no-max softmax: 1 exp/lane, logit[act] via v_readlane. ~31 DS ops/step (was ~58).
__global__ __launch_bounds__(64, 3) void rollout_kernel(
    const float* __restrict__ xi, const float* __restrict__ hid0,
    const float* __restrict__ dones, const int* __restrict__ actions,
    const float* __restrict__ Whrz, const float* __restrict__ Whn,
    const float* __restrict__ bhn, const float* __restrict__ Wout,
    const float* __restrict__ bout, float* __restrict__ out,
    unsigned int* __restrict__ ctr) {
  __shared__ __attribute__((aligned(16))) h2 sWo2[18 * 40];  // row j at [j*40], 32 pairs used
  __shared__ __attribute__((aligned(16))) h2 sh2[32];        // packed h broadcast
  __shared__ __attribute__((aligned(16))) float sloge[20];   // exp(logit); [18],[19]=0
  int lane = threadIdx.x;
  h2 Wr[32], Wz[32], Wn[32];     // f16-packed recurrent columns: 96 VGPRs
  #pragma unroll
  for (int k = 0; k < 32; ++k) {
    Wr[k] = h2{(_Float16)Whrz[(2 * k) * 128 + lane],      (_Float16)Whrz[(2 * k + 1) * 128 + lane]};
    Wz[k] = h2{(_Float16)Whrz[(2 * k) * 128 + 64 + lane], (_Float16)Whrz[(2 * k + 1) * 128 + 64 + lane]};
    Wn[k] = h2{(_Float16)Whn[(2 * k) * 64 + lane],        (_Float16)Whn[(2 * k + 1) * 64 + lane]};
  }
  for (int i = lane; i < 18 * 32; i += 64) {
    int j = i >> 5, p = i & 31;
    sWo2[j * 40 + p] = h2{(_Float16)Wout[(2 * p) * 18 + j], (_Float16)Wout[(2 * p + 1) * 18 + j]};
  }
  if (lane < 2) sloge[18 + lane] = 0.f;          // sentinels: exp contribution 0
  float bhn_r = bhn[lane];
  int row = (lane < 18) ? lane : 0;
  float bo_r = bout[row];
  __syncthreads();
  const uint4* shv  = (const uint4*)sh2;
  const uint4* wrow = (const uint4*)&sWo2[row * 40];
  while (true) {
    int i = 0;
    if (lane == 0) i = (int)atomicAdd(ctr, 1u);
    i = __shfl(i, 0);
    if (i >= 8192) break;
    int t = i >> 6, b = i & 63;                  // t-ascending = longest-first (LPT)
    int u = t;
    int pr = (t << 6) | b;
    float h = hid0[pr * 64 + lane];              // covers the s=0 reset case too
    const float* xb = xi + pr * 192;
    float x0 = xb[lane], x1 = xb[64 + lane], x2 = xb[128 + lane];
    float d = dones[pr];
    int  act = actions[pr];
    if ((lane & 1) == 0) sh2[lane >> 1] = pack_pair(h);
    for (int s = 0;; ++s) {
      int un = (u < 127) ? u + 1 : 127;
      int prn = (un << 6) | b;
      // -------- prefetch next step (hidden under compute) --------
      const float* xn = xi + prn * 192;
      float nx0 = xn[lane], nx1 = xn[64 + lane], nx2 = xn[128 + lane];
      float nd = dones[prn];
      int   na = actions[prn];
      float nh = hid0[prn * 64 + lane];
      // -------- GRU gates: 8 uniform b128 reads + 96 dot2 --------
      float ara = x0, arb = 0.f, aza = x1, azb = 0.f, ana = 0.f, anb = 0.f;
      #pragma unroll
      for (int q = 0; q < 8; ++q) {
        uint4 hv = shv[q];                        // broadcast (same addr all lanes)
        h2 a0 = __builtin_bit_cast(h2, hv.x);
        h2 a1 = __builtin_bit_cast(h2, hv.y);
        h2 a2 = __builtin_bit_cast(h2, hv.z);
        h2 a3 = __builtin_bit_cast(h2, hv.w);
        ara = DOT2(a0, Wr[4 * q + 0], ara); arb = DOT2(a1, Wr[4 * q + 1], arb);
        ara = DOT2(a2, Wr[4 * q + 2], ara); arb = DOT2(a3, Wr[4 * q + 3], arb);
        aza = DOT2(a0, Wz[4 * q + 0], aza); azb = DOT2(a1, Wz[4 * q + 1], azb);
        aza = DOT2(a2, Wz[4 * q + 2], aza); azb = DOT2(a3, Wz[4 * q + 3], azb);
        ana = DOT2(a0, Wn[4 * q + 0], ana); anb = DOT2(a1, Wn[4 * q + 1], anb);
        ana = DOT2(a2, Wn[4 * q + 2], ana); anb = DOT2(a3, Wn[4 * q + 3], anb);
      }
      float ar = ara + arb, az = aza + azb, an = ana + anb;
      float r = __builtin_amdgcn_rcpf(1.f + __expf(-ar));
      float z = __builtin_amdgcn_rcpf(1.f + __expf(-az));
      float pre = x2 + r * (an + bhn_r);
      float n = 1.f - 2.f * __builtin_amdgcn_rcpf(1.f + __expf(2.f * pre));  // tanh
      float hn = (1.f - z) * n + z * h;
      // -------- broadcast h_new; logits on all lanes (rows valid for lane<18) --------
      if ((lane & 1) == 0) sh2[lane >> 1] = pack_pair(hn);
      float la_a = bo_r, la_b = 0.f;
      #pragma unroll
      for (int q = 0; q < 8; ++q) {
        uint4 hv = shv[q];
        uint4 wv = wrow[q];
        la_a = DOT2(__builtin_bit_cast(h2, hv.x), __builtin_bit_cast(h2, wv.x), la_a);
        la_b = DOT2(__builtin_bit_cast(h2, hv.y), __builtin_bit_cast(h2, wv.y), la_b);
        la_a = DOT2(__builtin_bit_cast(h2, hv.z), __builtin_bit_cast(h2, wv.z), la_a);
        la_b = DOT2(__builtin_bit_cast(h2, hv.w), __builtin_bit_cast(h2, wv.w), la_b);
      }
      float logit = la_a + la_b;
      // -------- softmax without max pass (|logit| small by construction) --------
      if (lane < 18) sloge[lane] = __expf(logit);
      float4 e0 = *(const float4*)&sloge[0];
      float4 e1 = *(const float4*)&sloge[4];
      float4 e2 = *(const float4*)&sloge[8];
      float4 e3 = *(const float4*)&sloge[12];
      float4 e4 = *(const float4*)&sloge[16];    // [18],[19] are 0
      float ssum = (((e0.x + e0.y) + (e0.z + e0.w)) + ((e1.x + e1.y) + (e1.z + e1.w)))
                 + (((e2.x + e2.y) + (e2.z + e2.w)) + ((e3.x + e3.y) + (e3.z + e3.w)))
                 + ((e4.x + e4.y) + (e4.z + e4.w));
      float la = __builtin_bit_cast(float, __builtin_amdgcn_readlane(__builtin_bit_cast(int, logit), act));
      float lse = __logf(ssum);
      if (lane == 0) atomicAdd(&out[1 + s * 64 + b], lse - la);
      if (d > 0.f || u == 127) break;            // mask is 0 for all later steps
      // -------- advance --------
      u = un; x0 = nx0; x1 = nx1; x2 = nx2; d = nd; act = na;
      if (nd > 0.f) {
        h = nh;                                  // episode reset at next step start
        if ((lane & 1) == 0) sh2[lane >> 1] = pack_pair(h);
      } else {
        h = hn;                                  // sh2 already holds hn
      }
    }
  }
}

extern "C" void kernel_launch(void* const* d_in, const int* in_sizes, int n_in,
                              void* d_out, int out_size, void* d_ws, size_t ws_size,
                              hipStream_t stream) {
  const float* state = (const float*)d_in[0];
  const float* lm    = (const float*)d_in[1];
  const float* lv    = (const float*)d_in[2];
  const float* lmt   = (const float*)d_in[3];
  const float* lvt   = (const float*)d_in[4];
  const float* ac    = (const float*)d_in[5];
  const float* ms    = (const float*)d_in[6];
  const int*   actions = (const int*)d_in[7];
  const float* dones = (const float*)d_in[8];
  const float* Wst = (const float*)d_in[9],  *bst = (const float*)d_in[10];
  const float* Wac = (const float*)d_in[11], *bac = (const float*)d_in[12];
  const float* Wem = (const float*)d_in[13], *bem = (const float*)d_in[14];
  const float* Whd = (const float*)d_in[15], *bhd = (const float*)d_in[16];
  const float* Wi  = (const float*)d_in[17], *bi  = (const float*)d_in[18];
  const float* Whrz = (const float*)d_in[19];
  const float* Whn  = (const float*)d_in[20], *bhn = (const float*)d_in[21];
  const float* Wout = (const float*)d_in[22], *bout = (const float*)d_in[23];
  float* out = (float*)d_out;
  float* xi   = (float*)((char*)d_ws + XI_OFF);
  float* hid0 = (float*)((char*)d_ws + HID_OFF);
  unsigned int* ctr = (unsigned int*)((char*)d_ws + CTR_OFF);

  hipMemsetAsync(d_out, 0, (size_t)out_size * sizeof(float), stream);
  hipMemsetAsync(ctr, 0, sizeof(unsigned int), stream);

  hipLaunchKernelGGL(precompute_kernel, dim3(320), dim3(256), 0, stream,
                     state, ac, ms, Wst, bst, Wac, bac, Wem, bem, Whd, bhd, Wi, bi,
                     lm, lv, lmt, lvt, xi, hid0, out);
  hipLaunchKernelGGL(rollout_kernel, dim3(3072), dim3(64), 0, stream,
                     xi, hid0, dones, actions, Whrz, Whn, bhn, Wout, bout, out, ctr);
}

// Round 8
// 191.085 us; speedup vs baseline: 3.3074x; 1.9743x over previous
//
#include <hip/hip_runtime.h>

// Problem: T=128, B=64, STATE=32, LATENT=16, AC=8, MS=8, SE=64, AE=16, H=64, OUT=18
// d_out layout: [0] = kl_loss, [1 .. 8192] = recon_loss[s*64+b]  (out_size = 8193, f32)
// d_ws layout:  [0, 6291456)  xi  (T,B,192) f32   = embed@Wi + bi
//               [6291456, 8388608) hid0 (T,B,64) f32
//               [8388608, +4) work-steal counter

#define XI_OFF   0
#define HID_OFF  6291456
#define CTR_OFF  8388608

typedef float f32x16 __attribute__((ext_vector_type(16)));
typedef _Float16 h2 __attribute__((ext_vector_type(2)));

#if __has_builtin(__builtin_amdgcn_fdot2)
#define DOT2(a, b, c) __builtin_amdgcn_fdot2((a), (b), (c), false)
#else
#define DOT2(a, b, c) ((c) + (float)(a).x * (float)(b).x + (float)(a).y * (float)(b).y)
#endif

// pack {h[lane], h[lane^1]} into h2 using DPP quad_perm [1,0,3,2] (VALU, no LDS)
__device__ __forceinline__ h2 pack_pair(float h) {
  int hb = __builtin_bit_cast(int, h);
  int hp = __builtin_amdgcn_mov_dpp(hb, 0xB1, 0xF, 0xF, true);  // lane^1
  return __builtin_bit_cast(h2, __builtin_amdgcn_cvt_pkrtz(h, __builtin_bit_cast(float, hp)));
}

// ---------------- Fused precompute (blocks 0..255) + KL (blocks 256..319) ----------------
__global__ __launch_bounds__(256, 1) void precompute_kernel(
    const float* __restrict__ state, const float* __restrict__ ac, const float* __restrict__ ms,
    const float* __restrict__ Wst, const float* __restrict__ bst,
    const float* __restrict__ Wac, const float* __restrict__ bac,
    const float* __restrict__ Wem, const float* __restrict__ bem,
    const float* __restrict__ Whd, const float* __restrict__ bhd,
    const float* __restrict__ Wi,  const float* __restrict__ bi,
    const float* __restrict__ lm, const float* __restrict__ lv,
    const float* __restrict__ lmt, const float* __restrict__ lvt,
    float* __restrict__ xi, float* __restrict__ hid0, float* __restrict__ out) {
  __shared__ float sWst[32 * 64];
  __shared__ float sWem[80 * 64];
  __shared__ float sWhd[24 * 64];
  __shared__ float sWac[8 * 16];
  __shared__ float sb[208];
  __shared__ float sin_[4][48];
  __shared__ float sse[4][80];
  __shared__ float semb[4][64];
  __shared__ float ps[4];
  int tid = threadIdx.x, lane = tid & 63, w = tid >> 6;

  if (blockIdx.x >= 256) {
    // ---- KL: 64 blocks * 256 threads * 16 iters = 262144 items ----
    float total = 0.f;
    for (int it = 0; it < 16; ++it) {
      int idx = ((int)blockIdx.x - 256) * 256 + tid + it * 16384;
      int g = idx & 31;
      int pair = idx >> 5;
      const float* M = (g < 16) ? lm : lmt;
      const float* V = (g < 16) ? lv : lvt;
      int cur = pair * 16 + (g & 15);
      float mu = M[cur], lE = V[cur];
      float m = 0.f, lS = 0.f;
      if (pair >= 64) { m = M[cur - 1024]; lS = V[cur - 1024]; }
      float d = m - mu;
      total += 0.5f * (lS - lE - 1.f + __expf(lE - lS) + d * d * __expf(-lS));
    }
    #pragma unroll
    for (int off = 32; off; off >>= 1) total += __shfl_xor(total, off);
    if (lane == 0) ps[w] = total;
    __syncthreads();
    if (tid == 0) atomicAdd(out, ps[0] + ps[1] + ps[2] + ps[3]);
    return;
  }

  // ---- precompute: 32 (t,b) pairs per block ----
  f32x16 wi0[4], wi1[4], wi2[4];
  #pragma unroll
  for (int k = 0; k < 64; ++k) {
    wi0[k >> 4][k & 15] = Wi[k * 192 + lane];
    wi1[k >> 4][k & 15] = Wi[k * 192 + 64 + lane];
    wi2[k >> 4][k & 15] = Wi[k * 192 + 128 + lane];
  }
  for (int i = tid; i < 32 * 64; i += 256) sWst[i] = Wst[i];
  for (int i = tid; i < 80 * 64; i += 256) sWem[i] = Wem[i];
  for (int i = tid; i < 24 * 64; i += 256) sWhd[i] = Whd[i];
  for (int i = tid; i < 8 * 16; i += 256) sWac[i] = Wac[i];
  if (tid < 64) sb[tid] = bst[tid];
  if (tid < 16) sb[64 + tid] = bac[tid];
  if (tid < 64) sb[80 + tid] = bem[tid];
  if (tid < 64) sb[144 + tid] = bhd[tid];
  float bi0 = bi[lane], bi1 = bi[64 + lane], bi2 = bi[128 + lane];
  __syncthreads();
  for (int cnt = 0; cnt < 8; ++cnt) {
    int pair = blockIdx.x * 32 + w * 8 + cnt;   // t*64 + b, in [0, 8192)
    if (lane < 32)      sin_[w][lane] = state[pair * 32 + lane];
    else if (lane < 40) sin_[w][lane] = ac[pair * 8 + (lane - 32)];
    else if (lane < 48) sin_[w][lane] = ms[pair * 8 + (lane - 40)];
    __syncthreads();
    float se = sb[lane];
    #pragma unroll
    for (int k = 0; k < 32; ++k) se += sin_[w][k] * sWst[k * 64 + lane];
    se = fmaxf(se, 0.f);
    float ae = 0.f;
    if (lane < 16) {
      ae = sb[64 + lane];
      #pragma unroll
      for (int k = 0; k < 8; ++k) ae += sin_[w][32 + k] * sWac[k * 16 + lane];
      ae = fmaxf(ae, 0.f);
    }
    __syncthreads();
    sse[w][lane] = se;
    if (lane < 16) sse[w][64 + lane] = ae;
    __syncthreads();
    float em = sb[80 + lane];
    #pragma unroll
    for (int k = 0; k < 80; ++k) em += sse[w][k] * sWem[k * 64 + lane];
    float hd = sb[144 + lane];
    #pragma unroll
    for (int k = 0; k < 16; ++k) hd += sse[w][64 + k] * sWhd[k * 64 + lane];
    #pragma unroll
    for (int k = 0; k < 8; ++k) hd += sin_[w][40 + k] * sWhd[(16 + k) * 64 + lane];
    hid0[pair * 64 + lane] = hd;
    semb[w][lane] = em;
    __syncthreads();
    float x0 = bi0, x1 = bi1, x2 = bi2;
    #pragma unroll
    for (int k = 0; k < 64; ++k) {
      float e = semb[w][k];
      x0 += e * wi0[k >> 4][k & 15];
      x1 += e * wi1[k >> 4][k & 15];
      x2 += e * wi2[k >> 4][k & 15];
    }
    float* xo = xi + pair * 192;
    xo[lane] = x0; xo[64 + lane] = x1; xo[128 + lane] = x2;
    __syncthreads();
  }
}

// ---------------- Rollout: one wave per (t,b) sequence, work-stealing ----------------
// (64,2): 256-reg cap >> ~176 demand -> no spill, 2 waves/SIMD.
// f16 weights in regs: Wr/Wz/Wn (96) + Wout rows (32). h broadcast: DPP pack +
// 8 uniform b128 LDS reads per phase. ~24 DS ops/step.
__global__ __launch_bounds__(64, 2) void rollout_kernel(
    const float* __restrict__ xi, const float* __restrict__ hid0,
    const float* __restrict__ dones, const int* __restrict__ actions,
    const float* __restrict__ Whrz, const float* __restrict__ Whn,
    const float* __restrict__ bhn, const float* __restrict__ Wout,
    const float* __restrict__ bout, float* __restrict__ out,
    unsigned int* __restrict__ ctr) {
  __shared__ __attribute__((aligned(16))) h2 sh2[32];        // packed h broadcast
  __shared__ __attribute__((aligned(16))) float sloge[20];   // exp(logit); [18],[19]=0
  int lane = threadIdx.x;
  int row = (lane < 18) ? lane : 0;
  h2 Wr[32], Wz[32], Wn[32], Wo[32];   // f16-packed: 128 VGPRs total
  #pragma unroll
  for (int k = 0; k < 32; ++k) {
    Wr[k] = h2{(_Float16)Whrz[(2 * k) * 128 + lane],      (_Float16)Whrz[(2 * k + 1) * 128 + lane]};
    Wz[k] = h2{(_Float16)Whrz[(2 * k) * 128 + 64 + lane], (_Float16)Whrz[(2 * k + 1) * 128 + 64 + lane]};
    Wn[k] = h2{(_Float16)Whn[(2 * k) * 64 + lane],        (_Float16)Whn[(2 * k + 1) * 64 + lane]};
    Wo[k] = h2{(_Float16)Wout[(2 * k) * 18 + row],        (_Float16)Wout[(2 * k + 1) * 18 + row]};
  }
  if (lane < 2) sloge[18 + lane] = 0.f;          // sentinels: exp contribution 0
  float bhn_r = bhn[lane];
  float bo_r = bout[row];
  __syncthreads();
  const uint4* shv = (const uint4*)sh2;
  while (true) {
    int i = 0;
    if (lane == 0) i = (int)atomicAdd(ctr, 1u);
    i = __shfl(i, 0);
    if (i >= 8192) break;
    int t = i >> 6, b = i & 63;                  // t-ascending = longest-first (LPT)
    int u = t;
    int pr = (t << 6) | b;
    float h = hid0[pr * 64 + lane];              // covers the s=0 reset case too
    const float* xb = xi + pr * 192;
    float x0 = xb[lane], x1 = xb[64 + lane], x2 = xb[128 + lane];
    float d = dones[pr];
    int  act = actions[pr];
    if ((lane & 1) == 0) sh2[lane >> 1] = pack_pair(h);
    for (int s = 0;; ++s) {
      int un = (u < 127) ? u + 1 : 127;
      int prn = (un << 6) | b;
      // -------- prefetch next step (hidden under compute) --------
      const float* xn = xi + prn * 192;
      float nx0 = xn[lane], nx1 = xn[64 + lane], nx2 = xn[128 + lane];
      float nd = dones[prn];
      int   na = actions[prn];
      float nh = hid0[prn * 64 + lane];
      // -------- GRU gates: 8 uniform b128 reads + 96 dot2 --------
      float ara = x0, arb = 0.f, aza = x1, azb = 0.f, ana = 0.f, anb = 0.f;
      #pragma unroll
      for (int q = 0; q < 8; ++q) {
        uint4 hv = shv[q];                        // broadcast (same addr all lanes)
        h2 a0 = __builtin_bit_cast(h2, hv.x);
        h2 a1 = __builtin_bit_cast(h2, hv.y);
        h2 a2 = __builtin_bit_cast(h2, hv.z);
        h2 a3 = __builtin_bit_cast(h2, hv.w);
        ara = DOT2(a0, Wr[4 * q + 0], ara); arb = DOT2(a1, Wr[4 * q + 1], arb);
        ara = DOT2(a2, Wr[4 * q + 2], ara); arb = DOT2(a3, Wr[4 * q + 3], arb);
        aza = DOT2(a0, Wz[4 * q + 0], aza); azb = DOT2(a1, Wz[4 * q + 1], azb);
        aza = DOT2(a2, Wz[4 * q + 2], aza); azb = DOT2(a3, Wz[4 * q + 3], azb);
        ana = DOT2(a0, Wn[4 * q + 0], ana); anb = DOT2(a1, Wn[4 * q + 1], anb);
        ana = DOT2(a2, Wn[4 * q + 2], ana); anb = DOT2(a3, Wn[4 * q + 3], anb);
      }
      float ar = ara + arb, az = aza + azb, an = ana + anb;
      float r = __builtin_amdgcn_rcpf(1.f + __expf(-ar));
      float z = __builtin_amdgcn_rcpf(1.f + __expf(-az));
      float pre = x2 + r * (an + bhn_r);
      float n = 1.f - 2.f * __builtin_amdgcn_rcpf(1.f + __expf(2.f * pre));  // tanh
      float hn = (1.f - z) * n + z * h;
      // -------- broadcast h_new; logits via register W_out rows --------
      if ((lane & 1) == 0) sh2[lane >> 1] = pack_pair(hn);
      float la_a = bo_r, la_b = 0.f;
      #pragma unroll
      for (int q = 0; q < 8; ++q) {
        uint4 hv = shv[q];
        la_a = DOT2(__builtin_bit_cast(h2, hv.x), Wo[4 * q + 0], la_a);
        la_b = DOT2(__builtin_bit_cast(h2, hv.y), Wo[4 * q + 1], la_b);
        la_a = DOT2(__builtin_bit_cast(h2, hv.z), Wo[4 * q + 2], la_a);
        la_b = DOT2(__builtin_bit_cast(h2, hv.w), Wo[4 * q + 3], la_b);
      }
      float logit = la_a + la_b;
      // -------- softmax without max pass (|logit| small by construction) --------
      if (lane < 18) sloge[lane] = __expf(logit);
      float4 e0 = *(const float4*)&sloge[0];
      float4 e1 = *(const float4*)&sloge[4];
      float4 e2 = *(const float4*)&sloge[8];
      float4 e3 = *(const float4*)&sloge[12];
      float4 e4 = *(const float4*)&sloge[16];    // [18],[19] are 0
      float ssum = (((e0.x + e0.y) + (e0.z + e0.w)) + ((e1.x + e1.y) + (e1.z + e1.w)))
                 + (((e2.x + e2.y) + (e2.z + e2.w)) + ((e3.x + e3.y) + (e3.z + e3.w)))
                 + ((e4.x + e4.y) + (e4.z + e4.w));
      float la = __builtin_bit_cast(float, __builtin_amdgcn_readlane(__builtin_bit_cast(int, logit), act));
      float lse = __logf(ssum);
      if (lane == 0) atomicAdd(&out[1 + s * 64 + b], lse - la);
      if (d > 0.f || u == 127) break;            // mask is 0 for all later steps
      // -------- advance --------
      u = un; x0 = nx0; x1 = nx1; x2 = nx2; d = nd; act = na;
      if (nd > 0.f) {
        h = nh;                                  // episode reset at next step start
        if ((lane & 1) == 0) sh2[lane >> 1] = pack_pair(h);
      } else {
        h = hn;                                  // sh2 already holds hn
      }
    }
  }
}

extern "C" void kernel_launch(void* const* d_in, const int* in_sizes, int n_in,
                              void* d_out, int out_size, void* d_ws, size_t ws_size,
                              hipStream_t stream) {
  const float* state = (const float*)d_in[0];
  const float* lm    = (const float*)d_in[1];
  const float* lv    = (const float*)d_in[2];
  const float* lmt   = (const float*)d_in[3];
  const float* lvt   = (const float*)d_in[4];
  const float* ac    = (const float*)d_in[5];
  const float* ms    = (const float*)d_in[6];
  const int*   actions = (const int*)d_in[7];
  const float* dones = (const float*)d_in[8];
  const float* Wst = (const float*)d_in[9],  *bst = (const float*)d_in[10];
  const float* Wac = (const float*)d_in[11], *bac = (const float*)d_in[12];
  const float* Wem = (const float*)d_in[13], *bem = (const float*)d_in[14];
  const float* Whd = (const float*)d_in[15], *bhd = (const float*)d_in[16];
  const float* Wi  = (const float*)d_in[17], *bi  = (const float*)d_in[18];
  const float* Whrz = (const float*)d_in[19];
  const float* Whn  = (const float*)d_in[20], *bhn = (const float*)d_in[21];
  const float* Wout = (const float*)d_in[22], *bout = (const float*)d_in[23];
  float* out = (float*)d_out;
  float* xi   = (float*)((char*)d_ws + XI_OFF);
  float* hid0 = (float*)((char*)d_ws + HID_OFF);
  unsigned int* ctr = (unsigned int*)((char*)d_ws + CTR_OFF);

  hipMemsetAsync(d_out, 0, (size_t)out_size * sizeof(float), stream);
  hipMemsetAsync(ctr, 0, sizeof(unsigned int), stream);

  hipLaunchKernelGGL(precompute_kernel, dim3(320), dim3(256), 0, stream,
                     state, ac, ms, Wst, bst, Wac, bac, Wem, bem, Whd, bhd, Wi, bi,
                     lm, lv, lmt, lvt, xi, hid0, out);
  hipLaunchKernelGGL(rollout_kernel, dim3(2048), dim3(64), 0, stream,
                     xi, hid0, dones, actions, Whrz, Whn, bhn, Wout, bout, out, ctr);
}